// Round 1
// baseline (304.942 us; speedup 1.0000x reference)
//
#include <hip/hip_runtime.h>

// Problem constants (from setup_inputs):
//   H=8 heads, BATCH=4, N=4096, B=4 basis, T=512 timesteps
//   sites S = BATCH*N = 16384 independent recurrences
// Strategy: split T into CHUNKS chunks of L steps. Phase 1: each (site,chunk)
// thread computes the chunk-local spike partial sum P_k = sum d^(L-1-j) s_j
// (h-independent) into LDS. Phase 2: combine prior chunks' P to get the
// chunk-start state, then replay L steps emitting the H responses per step.
#define HH 8
#define BB 4
#define TT 512
#define CHUNKS 16
#define LL (TT / CHUNKS)   // 32
#define SPB 64             // sites per block (one wave per chunk)

__global__ __launch_bounds__(CHUNKS * SPB)
void temporal_basis_kernel(const float* __restrict__ z0,
                           const float* __restrict__ spikes,
                           const float* __restrict__ taus,
                           const float* __restrict__ coeffs,
                           const int* __restrict__ dt_p,
                           float* __restrict__ out,
                           int S) {
    __shared__ float4 lds_P[CHUNKS][SPB];

    const int chunk = threadIdx.x >> 6;           // wave id == chunk id
    const int sl    = threadIdx.x & 63;
    const int site  = blockIdx.x * SPB + sl;

    // decay factors d_k = exp(-dt / tau_k)
    const float dt = (float)dt_p[0];
    float d[BB];
#pragma unroll
    for (int k = 0; k < BB; ++k) d[k] = expf(-dt / taus[k]);

    // ---- Phase 1: chunk-local partial sums (h-independent) ----
    const int t0 = chunk * LL;
    float P[BB] = {0.f, 0.f, 0.f, 0.f};
    const float* __restrict__ sp = spikes + (size_t)t0 * S + site;
    for (int i = 0; i < LL; ++i) {
        const float s = sp[(size_t)i * S];
#pragma unroll
        for (int k = 0; k < BB; ++k) P[k] = d[k] * P[k] + s;
    }
    lds_P[chunk][sl] = make_float4(P[0], P[1], P[2], P[3]);
    __syncthreads();

    // d^L via 5 squarings (L = 32)
    float dL[BB];
#pragma unroll
    for (int k = 0; k < BB; ++k) {
        float x = d[k];
        x = x * x; x = x * x; x = x * x; x = x * x; x = x * x;
        dL[k] = x;
    }

    // ---- Phase 2: combine prior chunks -> spike-driven state at t0 ----
    float A[BB] = {0.f, 0.f, 0.f, 0.f};
    for (int e = 0; e < chunk; ++e) {
        const float4 p = lds_P[e][sl];
        A[0] = dL[0] * A[0] + p.x;
        A[1] = dL[1] * A[1] + p.y;
        A[2] = dL[2] * A[2] + p.z;
        A[3] = dL[3] * A[3] + p.w;
    }

    // d^(t0) = (d^L)^chunk
    float dt0[BB] = {1.f, 1.f, 1.f, 1.f};
    for (int e = 0; e < chunk; ++e) {
#pragma unroll
        for (int k = 0; k < BB; ++k) dt0[k] *= dL[k];
    }

    // init z[h][k] = d^(t0) * z0[h][k] + A[k]
    float z[HH][BB];
#pragma unroll
    for (int h = 0; h < HH; ++h) {
        const float4 zv = ((const float4*)z0)[(size_t)h * S + site];
        z[h][0] = dt0[0] * zv.x + A[0];
        z[h][1] = dt0[1] * zv.y + A[1];
        z[h][2] = dt0[2] * zv.z + A[2];
        z[h][3] = dt0[3] * zv.w + A[3];
    }

    // mixing coefficients (uniform -> scalar loads)
    float c[HH][BB];
#pragma unroll
    for (int h = 0; h < HH; ++h)
#pragma unroll
        for (int k = 0; k < BB; ++k) c[h][k] = coeffs[h * BB + k];

    // ---- main replay loop: L steps, emit H responses per step ----
    float* __restrict__ op = out + (size_t)t0 * HH * S + site;
    float s = sp[0];
    for (int i = 0; i < LL; ++i) {
        // prefetch next spike before the compute burst
        float s_next = (i + 1 < LL) ? sp[(size_t)(i + 1) * S] : 0.f;
#pragma unroll
        for (int h = 0; h < HH; ++h) {
#pragma unroll
            for (int k = 0; k < BB; ++k) z[h][k] = d[k] * z[h][k] + s;
            const float r = z[h][0] * c[h][0] + z[h][1] * c[h][1] +
                            z[h][2] * c[h][2] + z[h][3] * c[h][3];
            op[(size_t)(i * HH + h) * S] = r;
        }
        s = s_next;
    }
}

extern "C" void kernel_launch(void* const* d_in, const int* in_sizes, int n_in,
                              void* d_out, int out_size, void* d_ws, size_t ws_size,
                              hipStream_t stream) {
    const float* z0     = (const float*)d_in[0];
    const float* spikes = (const float*)d_in[1];
    const float* taus   = (const float*)d_in[2];
    const float* coeffs = (const float*)d_in[3];
    const int*   dt_p   = (const int*)d_in[4];
    float* out = (float*)d_out;

    // sites = spikes_elems / T
    const int S = in_sizes[1] / TT;   // 16384
    const int grid = S / SPB;         // 256 blocks

    temporal_basis_kernel<<<grid, CHUNKS * SPB, 0, stream>>>(
        z0, spikes, taus, coeffs, dt_p, out, S);
}

// Round 2
// 299.472 us; speedup vs baseline: 1.0183x; 1.0183x over previous
//
#include <hip/hip_runtime.h>

// TemporalBasis: T=512, H=8, BATCH=4, N=4096, B=4; sites S = BATCH*N = 16384.
// z_{t+1} = d*z_t + s_t (per site, per basis k), resp[t][h] = dot(coeffs[h], z_{t+1}).
//
// Chunked-scan decomposition: 16 chunks x 32 steps per block of 64 sites.
// Phase 1: each (chunk,site) thread computes chunk-local partials
//   P_k = sum_j d_k^(L-1-j) s_j  -> LDS, and packs the 32 binary spikes into a
//   uint32 bitmask (spikes are exactly 0.0/1.0) so the replay loop needs NO
//   global loads.
// Phase 2: prefix-combine prior chunks' P from LDS -> chunk-start state, then
//   replay 32 steps emitting 8 head responses per step via non-temporal stores.
#define HH 8
#define BB 4
#define TT 512
#define CHUNKS 16
#define LL (TT / CHUNKS)   // 32
#define SPB 64             // sites per block (one wave per chunk)

__global__ __launch_bounds__(CHUNKS * SPB)
void temporal_basis_kernel(const float* __restrict__ z0,
                           const float* __restrict__ spikes,
                           const float* __restrict__ taus,
                           const float* __restrict__ coeffs,
                           const int* __restrict__ dt_p,
                           float* __restrict__ out,
                           int S) {
    __shared__ float4 lds_P[CHUNKS][SPB];

    const int chunk = threadIdx.x >> 6;           // wave id == chunk id
    const int sl    = threadIdx.x & 63;
    const int site  = blockIdx.x * SPB + sl;

    // decay factors d_k = exp(-dt / tau_k)
    const float dt = (float)dt_p[0];
    float d[BB];
#pragma unroll
    for (int k = 0; k < BB; ++k) d[k] = expf(-dt / taus[k]);

    // ---- Phase 1: chunk-local partial sums + spike bitmask ----
    const int t0 = chunk * LL;
    float P[BB] = {0.f, 0.f, 0.f, 0.f};
    unsigned mask = 0u;
    const float* __restrict__ sp = spikes + (size_t)t0 * S + site;
#pragma unroll
    for (int i = 0; i < LL; ++i) {
        const float s = sp[(size_t)i * S];
        mask |= (s != 0.f ? 1u : 0u) << i;
#pragma unroll
        for (int k = 0; k < BB; ++k) P[k] = d[k] * P[k] + s;
    }
    lds_P[chunk][sl] = make_float4(P[0], P[1], P[2], P[3]);
    __syncthreads();

    // d^L via 5 squarings (L = 32)
    float dL[BB];
#pragma unroll
    for (int k = 0; k < BB; ++k) {
        float x = d[k];
        x = x * x; x = x * x; x = x * x; x = x * x; x = x * x;
        dL[k] = x;
    }

    // ---- Phase 2: combine prior chunks -> spike-driven state at t0 ----
    float A[BB] = {0.f, 0.f, 0.f, 0.f};
    for (int e = 0; e < chunk; ++e) {
        const float4 p = lds_P[e][sl];
        A[0] = dL[0] * A[0] + p.x;
        A[1] = dL[1] * A[1] + p.y;
        A[2] = dL[2] * A[2] + p.z;
        A[3] = dL[3] * A[3] + p.w;
    }

    // d^(t0) = (d^L)^chunk
    float dt0[BB] = {1.f, 1.f, 1.f, 1.f};
    for (int e = 0; e < chunk; ++e) {
#pragma unroll
        for (int k = 0; k < BB; ++k) dt0[k] *= dL[k];
    }

    // init z[h][k] = d^(t0) * z0[h][k] + A[k]
    float z[HH][BB];
#pragma unroll
    for (int h = 0; h < HH; ++h) {
        const float4 zv = ((const float4*)z0)[(size_t)h * S + site];
        z[h][0] = dt0[0] * zv.x + A[0];
        z[h][1] = dt0[1] * zv.y + A[1];
        z[h][2] = dt0[2] * zv.z + A[2];
        z[h][3] = dt0[3] * zv.w + A[3];
    }

    // mixing coefficients (wave-uniform -> compiler keeps in SGPRs)
    float c[HH][BB];
#pragma unroll
    for (int h = 0; h < HH; ++h)
#pragma unroll
        for (int k = 0; k < BB; ++k) c[h][k] = coeffs[h * BB + k];

    // ---- replay loop: no global loads, stores only ----
    float* __restrict__ op = out + (size_t)t0 * HH * S + site;
#pragma unroll 4
    for (int i = 0; i < LL; ++i) {
        const float s = (mask & (1u << i)) ? 1.0f : 0.0f;
#pragma unroll
        for (int h = 0; h < HH; ++h) {
#pragma unroll
            for (int k = 0; k < BB; ++k) z[h][k] = d[k] * z[h][k] + s;
            const float r = z[h][0] * c[h][0] + z[h][1] * c[h][1] +
                            z[h][2] * c[h][2] + z[h][3] * c[h][3];
            __builtin_nontemporal_store(r, &op[(size_t)(i * HH + h) * S]);
        }
    }
}

extern "C" void kernel_launch(void* const* d_in, const int* in_sizes, int n_in,
                              void* d_out, int out_size, void* d_ws, size_t ws_size,
                              hipStream_t stream) {
    const float* z0     = (const float*)d_in[0];
    const float* spikes = (const float*)d_in[1];
    const float* taus   = (const float*)d_in[2];
    const float* coeffs = (const float*)d_in[3];
    const int*   dt_p   = (const int*)d_in[4];
    float* out = (float*)d_out;

    const int S = in_sizes[1] / TT;   // 16384 sites
    const int grid = S / SPB;         // 256 blocks

    temporal_basis_kernel<<<grid, CHUNKS * SPB, 0, stream>>>(
        z0, spikes, taus, coeffs, dt_p, out, S);
}